// Round 5
// baseline (3067.107 us; speedup 1.0000x reference)
//
#include <hip/hip_runtime.h>

#define N_NODESC 100000
#define N_EDGESC 600000
#define HDIM 128
#define H3 384
#define NUM_STEPSC 5

#define SCAN_BLOCK 256
#define SCAN_CHUNK 1024

__device__ __forceinline__ float sigmoidf_(float x) { return 1.0f / (1.0f + expf(-x)); }

// W_cT[k][o] = sum_m W_ih[o][m]*W_msg[m][k];  W_hhT[k][o] = W_hh[o][k];  b_c[o] = sum_m W_ih[o][m]*b_msg[m]
__global__ void prep_weights(const float* __restrict__ W_msg, const float* __restrict__ b_msg,
                             const float* __restrict__ W_ih, const float* __restrict__ W_hh,
                             float* __restrict__ W_cT, float* __restrict__ W_hhT, float* __restrict__ b_c)
{
    int tid = blockIdx.x * blockDim.x + threadIdx.x;
    if (tid >= HDIM * H3) return;
    int o = tid % H3;   // 0..383
    int k = tid / H3;   // 0..127
    float acc = 0.f;
    for (int m = 0; m < HDIM; ++m)
        acc = fmaf(W_ih[o*HDIM + m], W_msg[m*HDIM + k], acc);
    W_cT[k*H3 + o] = acc;
    W_hhT[k*H3 + o] = W_hh[o*HDIM + k];
    if (k == 0) {
        float bb = 0.f;
        for (int m = 0; m < HDIM; ++m) bb = fmaf(W_ih[o*HDIM + m], b_msg[m], bb);
        b_c[o] = bb;
    }
}

__global__ void hist_kernel(const int* __restrict__ eidx, int* __restrict__ deg)
{
    int e = blockIdx.x * blockDim.x + threadIdx.x;
    if (e < N_EDGESC) atomicAdd(&deg[eidx[e]], 1);
}

__global__ void scan_partial(const int* __restrict__ in, int* __restrict__ out,
                             int* __restrict__ bsums, int n)
{
    __shared__ int ts[SCAN_BLOCK];
    int tid = threadIdx.x;
    int base = blockIdx.x * SCAN_CHUNK + tid * 4;
    int v0 = (base+0 < n) ? in[base+0] : 0;
    int v1 = (base+1 < n) ? in[base+1] : 0;
    int v2 = (base+2 < n) ? in[base+2] : 0;
    int v3 = (base+3 < n) ? in[base+3] : 0;
    ts[tid] = v0+v1+v2+v3;
    __syncthreads();
    for (int off = 1; off < SCAN_BLOCK; off <<= 1) {
        int t = (tid >= off) ? ts[tid-off] : 0;
        __syncthreads();
        ts[tid] += t;
        __syncthreads();
    }
    int excl = (tid > 0) ? ts[tid-1] : 0;
    if (tid == SCAN_BLOCK-1) bsums[blockIdx.x] = ts[SCAN_BLOCK-1];
    if (base+0 < n) out[base+0] = excl;
    if (base+1 < n) out[base+1] = excl + v0;
    if (base+2 < n) out[base+2] = excl + v0 + v1;
    if (base+3 < n) out[base+3] = excl + v0 + v1 + v2;
}

__global__ void scan_sums(int* bsums, int nb)
{
    if (threadIdx.x == 0 && blockIdx.x == 0) {
        int run = 0;
        for (int b = 0; b < nb; ++b) { int t = bsums[b]; bsums[b] = run; run += t; }
    }
}

__global__ void scan_add(int* __restrict__ out, const int* __restrict__ bsums, int n)
{
    int i = blockIdx.x * blockDim.x + threadIdx.x;
    if (i < n) out[i] += bsums[i / SCAN_CHUNK];
}

__global__ void copy_cursor(const int* __restrict__ offs, int* __restrict__ cur)
{
    int i = blockIdx.x * blockDim.x + threadIdx.x;
    if (i < N_NODESC) cur[i] = offs[i];
}

__global__ void scatter_edges(const int* __restrict__ eidx, int* __restrict__ cur, int* __restrict__ cols)
{
    int e = blockIdx.x * blockDim.x + threadIdx.x;
    if (e < N_EDGESC) {
        int r = eidx[e];
        int c = eidx[N_EDGESC + e];
        int p = atomicAdd(&cur[r], 1);
        cols[p] = c;
    }
}

// S[i,:] = sum over incoming edges of h[col,:]   (CSR, no atomics)
__global__ void agg_kernel(const float* __restrict__ h, const int* __restrict__ offs,
                           const int* __restrict__ cols, float* __restrict__ S)
{
    int node = blockIdx.x * 2 + (threadIdx.x >> 7);
    int j = threadIdx.x & (HDIM - 1);
    int beg = offs[node], end = offs[node+1];
    float a0 = 0.f, a1 = 0.f;
    int e = beg;
    for (; e + 1 < end; e += 2) {
        int c0 = cols[e], c1 = cols[e+1];
        a0 += h[(size_t)c0*HDIM + j];
        a1 += h[(size_t)c1*HDIM + j];
    }
    if (e < end) a0 += h[(size_t)cols[e]*HDIM + j];
    S[(size_t)node*HDIM + j] = a0 + a1;
}

// Fused GEMMs + GRU gates. 16 nodes per block, 384 threads (one per output column).
// gi = W_c * S_i + deg_i*b_c + b_ih ;  gh = W_hh * h_i + b_hh ;  gates (r,z,n) ; in-place h update.
#define GRU_NT 16
__global__ __launch_bounds__(384) void gru_kernel(
    const float* __restrict__ S, float* __restrict__ h,
    const int* __restrict__ deg,
    const float* __restrict__ W_cT, const float* __restrict__ W_hhT,
    const float* __restrict__ b_c, const float* __restrict__ b_ih, const float* __restrict__ b_hh)
{
    __shared__ float Sl[GRU_NT][HDIM];
    __shared__ float Hl[GRU_NT][HDIM];
    __shared__ float RZ[GRU_NT][2*HDIM];
    __shared__ float NIn[GRU_NT][HDIM];
    __shared__ float NHn[GRU_NT][HDIM];

    int tid = threadIdx.x;
    int i0 = blockIdx.x * GRU_NT;

    for (int idx = tid; idx < GRU_NT*HDIM; idx += 384) {
        int n = idx >> 7, k = idx & (HDIM-1);
        int node = i0 + n;
        Sl[n][k] = S[(size_t)node*HDIM + k];
        Hl[n][k] = h[(size_t)node*HDIM + k];
    }
    __syncthreads();

    int j = tid;  // 0..383 output column
    float acc_i[GRU_NT], acc_h[GRU_NT];
    #pragma unroll
    for (int n = 0; n < GRU_NT; ++n) { acc_i[n] = 0.f; acc_h[n] = 0.f; }

    for (int k = 0; k < HDIM; k += 4) {
        float wc0 = W_cT[(k+0)*H3 + j];
        float wc1 = W_cT[(k+1)*H3 + j];
        float wc2 = W_cT[(k+2)*H3 + j];
        float wc3 = W_cT[(k+3)*H3 + j];
        float wh0 = W_hhT[(k+0)*H3 + j];
        float wh1 = W_hhT[(k+1)*H3 + j];
        float wh2 = W_hhT[(k+2)*H3 + j];
        float wh3 = W_hhT[(k+3)*H3 + j];
        #pragma unroll
        for (int n = 0; n < GRU_NT; ++n) {
            float4 s4 = *reinterpret_cast<const float4*>(&Sl[n][k]);
            float4 h4 = *reinterpret_cast<const float4*>(&Hl[n][k]);
            acc_i[n] = fmaf(s4.x, wc0, acc_i[n]);
            acc_i[n] = fmaf(s4.y, wc1, acc_i[n]);
            acc_i[n] = fmaf(s4.z, wc2, acc_i[n]);
            acc_i[n] = fmaf(s4.w, wc3, acc_i[n]);
            acc_h[n] = fmaf(h4.x, wh0, acc_h[n]);
            acc_h[n] = fmaf(h4.y, wh1, acc_h[n]);
            acc_h[n] = fmaf(h4.z, wh2, acc_h[n]);
            acc_h[n] = fmaf(h4.w, wh3, acc_h[n]);
        }
    }

    float bcj  = b_c[j];
    float bihj = b_ih[j];
    float bhhj = b_hh[j];

    if (j < 2*HDIM) {
        #pragma unroll
        for (int n = 0; n < GRU_NT; ++n) {
            float dg = (float)deg[i0 + n];
            RZ[n][j] = acc_i[n] + dg*bcj + bihj + acc_h[n] + bhhj;
        }
    } else {
        int c = j - 2*HDIM;
        #pragma unroll
        for (int n = 0; n < GRU_NT; ++n) {
            float dg = (float)deg[i0 + n];
            NIn[n][c] = acc_i[n] + dg*bcj + bihj;
            NHn[n][c] = acc_h[n] + bhhj;
        }
    }
    __syncthreads();

    for (int idx = tid; idx < GRU_NT*HDIM; idx += 384) {
        int n = idx >> 7, c = idx & (HDIM-1);
        int node = i0 + n;
        float r  = sigmoidf_(RZ[n][c]);
        float z  = sigmoidf_(RZ[n][HDIM + c]);
        float nn = tanhf(NIn[n][c] + r * NHn[n][c]);
        h[(size_t)node*HDIM + c] = (1.f - z)*nn + z*Hl[n][c];
    }
}

extern "C" void kernel_launch(void* const* d_in, const int* in_sizes, int n_in,
                              void* d_out, int out_size, void* d_ws, size_t ws_size,
                              hipStream_t stream)
{
    const float* x     = (const float*)d_in[0];
    const int*   eidx  = (const int*)d_in[1];   // [2, E] int32 (harness converts integer inputs)
    const float* W_msg = (const float*)d_in[2];
    const float* b_msg = (const float*)d_in[3];
    const float* W_ih  = (const float*)d_in[4];
    const float* W_hh  = (const float*)d_in[5];
    const float* b_ih  = (const float*)d_in[6];
    const float* b_hh  = (const float*)d_in[7];

    float* h = (float*)d_out;   // h lives in d_out (in-place GRU is safe: cross-node coupling only via S)

    char* ws = (char*)d_ws;
    size_t off = 0;
    auto alloc = [&](size_t bytes) -> void* {
        void* p = ws + off;
        off = (off + bytes + 255) & ~(size_t)255;
        return p;
    };
    float* S      = (float*)alloc((size_t)N_NODESC*HDIM*sizeof(float));
    float* W_cT   = (float*)alloc((size_t)HDIM*H3*sizeof(float));
    float* W_hhT  = (float*)alloc((size_t)HDIM*H3*sizeof(float));
    float* b_c    = (float*)alloc(H3*sizeof(float));
    int*   deg    = (int*)alloc((N_NODESC+1)*sizeof(int));
    int*   offs   = (int*)alloc((N_NODESC+1)*sizeof(int));
    int*   cur    = (int*)alloc(N_NODESC*sizeof(int));
    int*   cols   = (int*)alloc(N_EDGESC*sizeof(int));
    int*   bsums  = (int*)alloc(256*sizeof(int));

    hipMemcpyAsync(h, x, (size_t)N_NODESC*HDIM*sizeof(float), hipMemcpyDeviceToDevice, stream);
    hipMemsetAsync(deg, 0, (N_NODESC+1)*sizeof(int), stream);

    prep_weights<<<(HDIM*H3 + 255)/256, 256, 0, stream>>>(W_msg, b_msg, W_ih, W_hh, W_cT, W_hhT, b_c);

    hist_kernel<<<(N_EDGESC + 255)/256, 256, 0, stream>>>(eidx, deg);

    int n_scan = N_NODESC + 1;
    int nb = (n_scan + SCAN_CHUNK - 1) / SCAN_CHUNK;
    scan_partial<<<nb, SCAN_BLOCK, 0, stream>>>(deg, offs, bsums, n_scan);
    scan_sums<<<1, 64, 0, stream>>>(bsums, nb);
    scan_add<<<(n_scan + 255)/256, 256, 0, stream>>>(offs, bsums, n_scan);

    copy_cursor<<<(N_NODESC + 255)/256, 256, 0, stream>>>(offs, cur);
    scatter_edges<<<(N_EDGESC + 255)/256, 256, 0, stream>>>(eidx, cur, cols);

    for (int step = 0; step < NUM_STEPSC; ++step) {
        agg_kernel<<<N_NODESC/2, 256, 0, stream>>>(h, offs, cols, S);
        gru_kernel<<<N_NODESC/GRU_NT, 384, 0, stream>>>(S, h, deg, W_cT, W_hhT, b_c, b_ih, b_hh);
    }
}

// Round 6
// 631.382 us; speedup vs baseline: 4.8578x; 4.8578x over previous
//
#include <hip/hip_runtime.h>

#define N_NODESC 100000
#define N_EDGESC 600000
#define HDIM 128
#define H3 384
#define NUM_STEPSC 5

#define SCAN_BLOCK 256
#define SCAN_CHUNK 1024

typedef __attribute__((ext_vector_type(8))) short bf16x8;
typedef __attribute__((ext_vector_type(4))) float f32x4;

__device__ __forceinline__ float sigmoidf_(float x) { return 1.0f / (1.0f + expf(-x)); }

__device__ __forceinline__ unsigned short f2bf(float x) {
    union { float f; unsigned int u; } v; v.f = x;
    unsigned int r = v.u + 0x7FFF + ((v.u >> 16) & 1);
    return (unsigned short)(r >> 16);
}
__device__ __forceinline__ float bf2f(unsigned int lo16) {
    union { unsigned int u; float f; } v; v.u = lo16 << 16; return v.f;
}

// ---- weight prep: W_c = W_ih @ W_msg (fused), pack W_c and W_hh^T into MFMA B-frag layout ----
// B-frag layout for mfma_f32_16x16x32_bf16: lane = (k_in_tile/8)*16 + (j&15), elem e = k_in_tile&7.
// flat index: ((kt*24 + jt)*64 + lane)*8 + e   (kt = k>>5, jt = j>>4)
__global__ void prep_pack(const float* __restrict__ W_msg, const float* __restrict__ b_msg,
                          const float* __restrict__ W_ih, const float* __restrict__ W_hh,
                          unsigned short* __restrict__ Wc, unsigned short* __restrict__ Wh,
                          float* __restrict__ b_c)
{
    int tid = blockIdx.x * blockDim.x + threadIdx.x;
    if (tid >= HDIM * H3) return;
    int j = tid % H3;   // output col 0..383
    int k = tid / H3;   // input dim 0..127
    float wc = 0.f;
    for (int m = 0; m < HDIM; ++m)
        wc = fmaf(W_ih[j*HDIM + m], W_msg[m*HDIM + k], wc);
    float wh = W_hh[j*HDIM + k];
    int kt = k >> 5, kk = k & 31, jt = j >> 4, jj = j & 15;
    int lane = ((kk >> 3) << 4) + jj;
    int e = kk & 7;
    size_t idx = ((size_t)(kt*24 + jt)*64 + lane)*8 + e;
    Wc[idx] = f2bf(wc);
    Wh[idx] = f2bf(wh);
    if (k == 0) {
        float bb = 0.f;
        for (int m = 0; m < HDIM; ++m) bb = fmaf(W_ih[j*HDIM + m], b_msg[m], bb);
        b_c[j] = bb;
    }
}

// ---- h init: fp32 copy into d_out + bf16 shadow ----
__global__ void init_h(const float* __restrict__ x, float* __restrict__ h, unsigned short* __restrict__ h_bf)
{
    int i = blockIdx.x * blockDim.x + threadIdx.x;
    if (i >= N_NODESC * HDIM / 4) return;
    float4 v = ((const float4*)x)[i];
    ((float4*)h)[i] = v;
    ushort4 b;
    b.x = f2bf(v.x); b.y = f2bf(v.y); b.z = f2bf(v.z); b.w = f2bf(v.w);
    ((ushort4*)h_bf)[i] = b;
}

// ---- CSR build ----
__global__ void hist_kernel(const int* __restrict__ eidx, int* __restrict__ deg)
{
    int e = blockIdx.x * blockDim.x + threadIdx.x;
    if (e < N_EDGESC) atomicAdd(&deg[eidx[e]], 1);
}

__global__ void scan_partial(const int* __restrict__ in, int* __restrict__ out,
                             int* __restrict__ bsums, int n)
{
    __shared__ int ts[SCAN_BLOCK];
    int tid = threadIdx.x;
    int base = blockIdx.x * SCAN_CHUNK + tid * 4;
    int v0 = (base+0 < n) ? in[base+0] : 0;
    int v1 = (base+1 < n) ? in[base+1] : 0;
    int v2 = (base+2 < n) ? in[base+2] : 0;
    int v3 = (base+3 < n) ? in[base+3] : 0;
    ts[tid] = v0+v1+v2+v3;
    __syncthreads();
    for (int off = 1; off < SCAN_BLOCK; off <<= 1) {
        int t = (tid >= off) ? ts[tid-off] : 0;
        __syncthreads();
        ts[tid] += t;
        __syncthreads();
    }
    int excl = (tid > 0) ? ts[tid-1] : 0;
    if (tid == SCAN_BLOCK-1) bsums[blockIdx.x] = ts[SCAN_BLOCK-1];
    if (base+0 < n) out[base+0] = excl;
    if (base+1 < n) out[base+1] = excl + v0;
    if (base+2 < n) out[base+2] = excl + v0 + v1;
    if (base+3 < n) out[base+3] = excl + v0 + v1 + v2;
}

__global__ void scan_sums(int* bsums, int nb)
{
    if (threadIdx.x == 0 && blockIdx.x == 0) {
        int run = 0;
        for (int b = 0; b < nb; ++b) { int t = bsums[b]; bsums[b] = run; run += t; }
    }
}

__global__ void scan_add(int* __restrict__ out, const int* __restrict__ bsums, int n)
{
    int i = blockIdx.x * blockDim.x + threadIdx.x;
    if (i < n) out[i] += bsums[i / SCAN_CHUNK];
}

__global__ void copy_cursor(const int* __restrict__ offs, int* __restrict__ cur)
{
    int i = blockIdx.x * blockDim.x + threadIdx.x;
    if (i < N_NODESC) cur[i] = offs[i];
}

__global__ void scatter_edges(const int* __restrict__ eidx, int* __restrict__ cur, int* __restrict__ cols)
{
    int e = blockIdx.x * blockDim.x + threadIdx.x;
    if (e < N_EDGESC) {
        int r = eidx[e];
        int c = eidx[N_EDGESC + e];
        int p = atomicAdd(&cur[r], 1);
        cols[p] = c;
    }
}

// ---- aggregation: S_bf[i,:] = bf16( sum_{e in CSR(i)} fp32(h_bf[cols[e],:]) ) ----
__global__ void agg_bf16(const unsigned short* __restrict__ h_bf, const int* __restrict__ offs,
                         const int* __restrict__ cols, unsigned short* __restrict__ S_bf)
{
    int node = blockIdx.x * 4 + (threadIdx.x >> 6);
    int j2 = threadIdx.x & 63;                 // cols 2*j2, 2*j2+1
    int beg = offs[node], end = offs[node+1];
    float a0 = 0.f, a1 = 0.f, b0 = 0.f, b1 = 0.f;
    int e = beg;
    for (; e + 1 < end; e += 2) {
        int c0 = cols[e], c1 = cols[e+1];
        unsigned int u0 = *(const unsigned int*)(h_bf + (size_t)c0*HDIM + j2*2);
        unsigned int u1 = *(const unsigned int*)(h_bf + (size_t)c1*HDIM + j2*2);
        a0 += bf2f(u0 & 0xffffu); a1 += bf2f(u0 >> 16);
        b0 += bf2f(u1 & 0xffffu); b1 += bf2f(u1 >> 16);
    }
    if (e < end) {
        unsigned int u0 = *(const unsigned int*)(h_bf + (size_t)cols[e]*HDIM + j2*2);
        a0 += bf2f(u0 & 0xffffu); a1 += bf2f(u0 >> 16);
    }
    float s0 = a0 + b0, s1 = a1 + b1;
    unsigned int out = (unsigned int)f2bf(s0) | ((unsigned int)f2bf(s1) << 16);
    *(unsigned int*)(S_bf + (size_t)node*HDIM + j2*2) = out;
}

// ---- fused MFMA GEMMs + GRU gates ----
// 512 threads = 8 waves. Block tile: 32 nodes. Wave w owns col group c = w*16 + lane&15 and
// its r/z/n tiles (c, c+128, c+256) for BOTH GEMMs -> gate math is register-local in the
// C-layout (col=lane&15, row=(lane>>4)*4+q).
#define GRU_M 32
__global__ __launch_bounds__(512) void gru_mfma(
    const unsigned short* __restrict__ S_bf, float* __restrict__ h, unsigned short* __restrict__ h_bf,
    const int* __restrict__ deg,
    const unsigned short* __restrict__ Wc, const unsigned short* __restrict__ Wh,
    const float* __restrict__ b_c, const float* __restrict__ b_ih, const float* __restrict__ b_hh)
{
    __shared__ unsigned short Sl[GRU_M * HDIM];
    __shared__ unsigned short Hl[GRU_M * HDIM];

    int tid = threadIdx.x;
    int i0 = blockIdx.x * GRU_M;

    // stage S,h tiles (bf16, XOR-swizzled rows: byte ^= (row&7)<<4 breaks 256B-stride conflicts)
    {
        int srow = tid >> 4;
        int cb = (tid & 15) << 4;
        int pb = srow*256 + (cb ^ ((srow & 7) << 4));
        float4 vs = *(const float4*)((const char*)S_bf + (size_t)(i0 + srow)*256 + cb);
        float4 vh = *(const float4*)((const char*)h_bf + (size_t)(i0 + srow)*256 + cb);
        *(float4*)((char*)Sl + pb) = vs;
        *(float4*)((char*)Hl + pb) = vh;
    }
    __syncthreads();

    int lane = tid & 63;
    int wid  = tid >> 6;       // 0..7 -> col tile
    int kg   = lane >> 4;      // 0..3
    int lr   = lane & 15;

    f32x4 a_cr[2], a_cz[2], a_cn[2], a_hr[2], a_hz[2], a_hn[2];
    #pragma unroll
    for (int t = 0; t < 2; ++t) {
        a_cr[t] = (f32x4){0,0,0,0}; a_cz[t] = (f32x4){0,0,0,0}; a_cn[t] = (f32x4){0,0,0,0};
        a_hr[t] = (f32x4){0,0,0,0}; a_hz[t] = (f32x4){0,0,0,0}; a_hn[t] = (f32x4){0,0,0,0};
    }

    int r0 = lr, r1 = 16 + lr;
    int x0 = (r0 & 7) << 4, x1 = (r1 & 7) << 4;

    #pragma unroll
    for (int kc = 0; kc < 4; ++kc) {
        int cb = kc*64 + kg*16;
        bf16x8 aS0 = *(const bf16x8*)((const char*)Sl + r0*256 + (cb ^ x0));
        bf16x8 aS1 = *(const bf16x8*)((const char*)Sl + r1*256 + (cb ^ x1));
        bf16x8 aH0 = *(const bf16x8*)((const char*)Hl + r0*256 + (cb ^ x0));
        bf16x8 aH1 = *(const bf16x8*)((const char*)Hl + r1*256 + (cb ^ x1));
        const bf16x8* Bc = (const bf16x8*)Wc + (size_t)kc*1536 + lane;
        const bf16x8* Bh = (const bf16x8*)Wh + (size_t)kc*1536 + lane;
        bf16x8 b;
        b = Bc[(size_t)(wid     ) * 64];
        a_cr[0] = __builtin_amdgcn_mfma_f32_16x16x32_bf16(aS0, b, a_cr[0], 0, 0, 0);
        a_cr[1] = __builtin_amdgcn_mfma_f32_16x16x32_bf16(aS1, b, a_cr[1], 0, 0, 0);
        b = Bc[(size_t)(wid +  8) * 64];
        a_cz[0] = __builtin_amdgcn_mfma_f32_16x16x32_bf16(aS0, b, a_cz[0], 0, 0, 0);
        a_cz[1] = __builtin_amdgcn_mfma_f32_16x16x32_bf16(aS1, b, a_cz[1], 0, 0, 0);
        b = Bc[(size_t)(wid + 16) * 64];
        a_cn[0] = __builtin_amdgcn_mfma_f32_16x16x32_bf16(aS0, b, a_cn[0], 0, 0, 0);
        a_cn[1] = __builtin_amdgcn_mfma_f32_16x16x32_bf16(aS1, b, a_cn[1], 0, 0, 0);
        b = Bh[(size_t)(wid     ) * 64];
        a_hr[0] = __builtin_amdgcn_mfma_f32_16x16x32_bf16(aH0, b, a_hr[0], 0, 0, 0);
        a_hr[1] = __builtin_amdgcn_mfma_f32_16x16x32_bf16(aH1, b, a_hr[1], 0, 0, 0);
        b = Bh[(size_t)(wid +  8) * 64];
        a_hz[0] = __builtin_amdgcn_mfma_f32_16x16x32_bf16(aH0, b, a_hz[0], 0, 0, 0);
        a_hz[1] = __builtin_amdgcn_mfma_f32_16x16x32_bf16(aH1, b, a_hz[1], 0, 0, 0);
        b = Bh[(size_t)(wid + 16) * 64];
        a_hn[0] = __builtin_amdgcn_mfma_f32_16x16x32_bf16(aH0, b, a_hn[0], 0, 0, 0);
        a_hn[1] = __builtin_amdgcn_mfma_f32_16x16x32_bf16(aH1, b, a_hn[1], 0, 0, 0);
    }

    int c = (wid << 4) + lr;
    float bc_r = b_c[c],        bc_z = b_c[c+128],  bc_n = b_c[c+256];
    float bi_r = b_ih[c],       bi_z = b_ih[c+128], bi_n = b_ih[c+256];
    float bh_r = b_hh[c],       bh_z = b_hh[c+128], bh_n = b_hh[c+256];

    #pragma unroll
    for (int t = 0; t < 2; ++t) {
        #pragma unroll
        for (int q = 0; q < 4; ++q) {
            int node = i0 + t*16 + (kg << 2) + q;
            float dg = (float)deg[node];
            float gir = a_cr[t][q] + dg*bc_r + bi_r;
            float giz = a_cz[t][q] + dg*bc_z + bi_z;
            float gin = a_cn[t][q] + dg*bc_n + bi_n;
            float ghr = a_hr[t][q] + bh_r;
            float ghz = a_hz[t][q] + bh_z;
            float ghn = a_hn[t][q] + bh_n;
            float r = sigmoidf_(gir + ghr);
            float z = sigmoidf_(giz + ghz);
            float nn = tanhf(gin + r * ghn);
            size_t p = (size_t)node*HDIM + c;
            float ho = h[p];
            float hv = (1.f - z)*nn + z*ho;
            h[p] = hv;
            h_bf[p] = f2bf(hv);
        }
    }
}

extern "C" void kernel_launch(void* const* d_in, const int* in_sizes, int n_in,
                              void* d_out, int out_size, void* d_ws, size_t ws_size,
                              hipStream_t stream)
{
    const float* x     = (const float*)d_in[0];
    const int*   eidx  = (const int*)d_in[1];
    const float* W_msg = (const float*)d_in[2];
    const float* b_msg = (const float*)d_in[3];
    const float* W_ih  = (const float*)d_in[4];
    const float* W_hh  = (const float*)d_in[5];
    const float* b_ih  = (const float*)d_in[6];
    const float* b_hh  = (const float*)d_in[7];

    float* h = (float*)d_out;

    char* ws = (char*)d_ws;
    size_t off = 0;
    auto alloc = [&](size_t bytes) -> void* {
        void* p = ws + off;
        off = (off + bytes + 255) & ~(size_t)255;
        return p;
    };
    unsigned short* S_bf = (unsigned short*)alloc((size_t)N_NODESC*HDIM*sizeof(unsigned short));
    unsigned short* h_bf = (unsigned short*)alloc((size_t)N_NODESC*HDIM*sizeof(unsigned short));
    unsigned short* Wc   = (unsigned short*)alloc((size_t)HDIM*H3*sizeof(unsigned short));
    unsigned short* Wh   = (unsigned short*)alloc((size_t)HDIM*H3*sizeof(unsigned short));
    float* b_c    = (float*)alloc(H3*sizeof(float));
    int*   deg    = (int*)alloc((N_NODESC+1)*sizeof(int));
    int*   offs   = (int*)alloc((N_NODESC+1)*sizeof(int));
    int*   cur    = (int*)alloc(N_NODESC*sizeof(int));
    int*   cols   = (int*)alloc(N_EDGESC*sizeof(int));
    int*   bsums  = (int*)alloc(256*sizeof(int));

    hipMemsetAsync(deg, 0, (N_NODESC+1)*sizeof(int), stream);

    init_h<<<(N_NODESC*HDIM/4 + 255)/256, 256, 0, stream>>>(x, h, h_bf);
    prep_pack<<<(HDIM*H3 + 255)/256, 256, 0, stream>>>(W_msg, b_msg, W_ih, W_hh, Wc, Wh, b_c);

    hist_kernel<<<(N_EDGESC + 255)/256, 256, 0, stream>>>(eidx, deg);

    int n_scan = N_NODESC + 1;
    int nb = (n_scan + SCAN_CHUNK - 1) / SCAN_CHUNK;
    scan_partial<<<nb, SCAN_BLOCK, 0, stream>>>(deg, offs, bsums, n_scan);
    scan_sums<<<1, 64, 0, stream>>>(bsums, nb);
    scan_add<<<(n_scan + 255)/256, 256, 0, stream>>>(offs, bsums, n_scan);

    copy_cursor<<<(N_NODESC + 255)/256, 256, 0, stream>>>(offs, cur);
    scatter_edges<<<(N_EDGESC + 255)/256, 256, 0, stream>>>(eidx, cur, cols);

    for (int step = 0; step < NUM_STEPSC; ++step) {
        agg_bf16<<<N_NODESC/4, 256, 0, stream>>>(h_bf, offs, cols, S_bf);
        gru_mfma<<<N_NODESC/GRU_M, 512, 0, stream>>>(S_bf, h, h_bf, deg, Wc, Wh, b_c, b_ih, b_hh);
    }
}

// Round 7
// 579.550 us; speedup vs baseline: 5.2922x; 1.0894x over previous
//
#include <hip/hip_runtime.h>

#define N_NODESC 100000
#define N_EDGESC 600000
#define HDIM 128
#define H3 384
#define NUM_STEPSC 5

#define SCAN_BLOCK 256
#define SCAN_CHUNK 1024

typedef __attribute__((ext_vector_type(8))) short bf16x8;
typedef __attribute__((ext_vector_type(4))) float f32x4;

__device__ __forceinline__ unsigned short f2bf(float x) {
    union { float f; unsigned int u; } v; v.f = x;
    unsigned int r = v.u + 0x7FFF + ((v.u >> 16) & 1);
    return (unsigned short)(r >> 16);
}
__device__ __forceinline__ float bf2f(unsigned int lo16) {
    union { unsigned int u; float f; } v; v.u = lo16 << 16; return v.f;
}

// hardware gates: v_exp_f32 computes 2^x, v_rcp_f32 ~1ulp. Saturation at +/-inf is exact.
__device__ __forceinline__ float fast_sigmoid(float x) {
    float e = __builtin_amdgcn_exp2f(-1.44269504f * x);
    return __builtin_amdgcn_rcpf(1.0f + e);
}
__device__ __forceinline__ float fast_tanh(float x) {
    float e = __builtin_amdgcn_exp2f(2.88539008f * x);
    return 1.0f - 2.0f * __builtin_amdgcn_rcpf(1.0f + e);
}

// ---- weight prep: W_c = W_ih @ W_msg (fused), pack W_c and W_hh^T into MFMA B-frag layout ----
// B-frag layout for mfma_f32_16x16x32_bf16: lane = (k_in_tile/8)*16 + (j&15), elem e = k_in_tile&7.
// flat index: ((kt*24 + jt)*64 + lane)*8 + e   (kt = k>>5, jt = j>>4)
__global__ void prep_pack(const float* __restrict__ W_msg, const float* __restrict__ b_msg,
                          const float* __restrict__ W_ih, const float* __restrict__ W_hh,
                          unsigned short* __restrict__ Wc, unsigned short* __restrict__ Wh,
                          float* __restrict__ b_c)
{
    int tid = blockIdx.x * blockDim.x + threadIdx.x;
    if (tid >= HDIM * H3) return;
    int j = tid % H3;   // output col 0..383
    int k = tid / H3;   // input dim 0..127
    float wc = 0.f;
    for (int m = 0; m < HDIM; ++m)
        wc = fmaf(W_ih[j*HDIM + m], W_msg[m*HDIM + k], wc);
    float wh = W_hh[j*HDIM + k];
    int kt = k >> 5, kk = k & 31, jt = j >> 4, jj = j & 15;
    int lane = ((kk >> 3) << 4) + jj;
    int e = kk & 7;
    size_t idx = ((size_t)(kt*24 + jt)*64 + lane)*8 + e;
    Wc[idx] = f2bf(wc);
    Wh[idx] = f2bf(wh);
    if (k == 0) {
        float bb = 0.f;
        for (int m = 0; m < HDIM; ++m) bb = fmaf(W_ih[j*HDIM + m], b_msg[m], bb);
        b_c[j] = bb;
    }
}

// ---- h init: fp32 copy into d_out + bf16 shadow ----
__global__ void init_h(const float* __restrict__ x, float* __restrict__ h, unsigned short* __restrict__ h_bf)
{
    int i = blockIdx.x * blockDim.x + threadIdx.x;
    if (i >= N_NODESC * HDIM / 4) return;
    float4 v = ((const float4*)x)[i];
    ((float4*)h)[i] = v;
    ushort4 b;
    b.x = f2bf(v.x); b.y = f2bf(v.y); b.z = f2bf(v.z); b.w = f2bf(v.w);
    ((ushort4*)h_bf)[i] = b;
}

// ---- CSR build ----
__global__ void hist_kernel(const int* __restrict__ eidx, int* __restrict__ deg)
{
    int e = blockIdx.x * blockDim.x + threadIdx.x;
    if (e < N_EDGESC) atomicAdd(&deg[eidx[e]], 1);
}

__global__ void scan_partial(const int* __restrict__ in, int* __restrict__ out,
                             int* __restrict__ bsums, int n)
{
    __shared__ int ts[SCAN_BLOCK];
    int tid = threadIdx.x;
    int base = blockIdx.x * SCAN_CHUNK + tid * 4;
    int v0 = (base+0 < n) ? in[base+0] : 0;
    int v1 = (base+1 < n) ? in[base+1] : 0;
    int v2 = (base+2 < n) ? in[base+2] : 0;
    int v3 = (base+3 < n) ? in[base+3] : 0;
    ts[tid] = v0+v1+v2+v3;
    __syncthreads();
    for (int off = 1; off < SCAN_BLOCK; off <<= 1) {
        int t = (tid >= off) ? ts[tid-off] : 0;
        __syncthreads();
        ts[tid] += t;
        __syncthreads();
    }
    int excl = (tid > 0) ? ts[tid-1] : 0;
    if (tid == SCAN_BLOCK-1) bsums[blockIdx.x] = ts[SCAN_BLOCK-1];
    if (base+0 < n) out[base+0] = excl;
    if (base+1 < n) out[base+1] = excl + v0;
    if (base+2 < n) out[base+2] = excl + v0 + v1;
    if (base+3 < n) out[base+3] = excl + v0 + v1 + v2;
}

__global__ void scan_sums(int* bsums, int nb)
{
    if (threadIdx.x == 0 && blockIdx.x == 0) {
        int run = 0;
        for (int b = 0; b < nb; ++b) { int t = bsums[b]; bsums[b] = run; run += t; }
    }
}

__global__ void scan_add(int* __restrict__ out, const int* __restrict__ bsums, int n)
{
    int i = blockIdx.x * blockDim.x + threadIdx.x;
    if (i < n) out[i] += bsums[i / SCAN_CHUNK];
}

__global__ void copy_cursor(const int* __restrict__ offs, int* __restrict__ cur)
{
    int i = blockIdx.x * blockDim.x + threadIdx.x;
    if (i < N_NODESC) cur[i] = offs[i];
}

__global__ void scatter_edges(const int* __restrict__ eidx, int* __restrict__ cur, int* __restrict__ cols)
{
    int e = blockIdx.x * blockDim.x + threadIdx.x;
    if (e < N_EDGESC) {
        int r = eidx[e];
        int c = eidx[N_EDGESC + e];
        int p = atomicAdd(&cur[r], 1);
        cols[p] = c;
    }
}

// ---- aggregation: S_bf[i,:] = bf16( sum_{e in CSR(i)} fp32(h_bf[cols[e],:]) ) ----
__global__ void agg_bf16(const unsigned short* __restrict__ h_bf, const int* __restrict__ offs,
                         const int* __restrict__ cols, unsigned short* __restrict__ S_bf)
{
    int node = blockIdx.x * 4 + (threadIdx.x >> 6);
    int j2 = threadIdx.x & 63;                 // cols 2*j2, 2*j2+1
    int beg = offs[node], end = offs[node+1];
    float a0 = 0.f, a1 = 0.f, b0 = 0.f, b1 = 0.f;
    int e = beg;
    for (; e + 1 < end; e += 2) {
        int c0 = cols[e], c1 = cols[e+1];
        unsigned int u0 = *(const unsigned int*)(h_bf + (size_t)c0*HDIM + j2*2);
        unsigned int u1 = *(const unsigned int*)(h_bf + (size_t)c1*HDIM + j2*2);
        a0 += bf2f(u0 & 0xffffu); a1 += bf2f(u0 >> 16);
        b0 += bf2f(u1 & 0xffffu); b1 += bf2f(u1 >> 16);
    }
    if (e < end) {
        unsigned int u0 = *(const unsigned int*)(h_bf + (size_t)cols[e]*HDIM + j2*2);
        a0 += bf2f(u0 & 0xffffu); a1 += bf2f(u0 >> 16);
    }
    float s0 = a0 + b0, s1 = a1 + b1;
    unsigned int out = (unsigned int)f2bf(s0) | ((unsigned int)f2bf(s1) << 16);
    *(unsigned int*)(S_bf + (size_t)node*HDIM + j2*2) = out;
}

// ---- fused MFMA GEMMs + GRU gates ----
// 512 threads = 8 waves. Block tile: 32 nodes. Wave w owns col group c = w*16 + lane&15 and
// its r/z/n tiles (c, c+128, c+256) for BOTH GEMMs -> gate math is register-local in the
// C-layout (col=lane&15, row=(lane>>4)*4+q).
#define GRU_M 32
__global__ __launch_bounds__(512) void gru_mfma(
    const unsigned short* __restrict__ S_bf, float* __restrict__ h, unsigned short* __restrict__ h_bf,
    const int* __restrict__ deg,
    const unsigned short* __restrict__ Wc, const unsigned short* __restrict__ Wh,
    const float* __restrict__ b_c, const float* __restrict__ b_ih, const float* __restrict__ b_hh)
{
    __shared__ unsigned short Sl[GRU_M * HDIM];
    __shared__ unsigned short Hl[GRU_M * HDIM];
    __shared__ float Dl[GRU_M];

    int tid = threadIdx.x;
    int i0 = blockIdx.x * GRU_M;

    int lane = tid & 63;
    int wid  = tid >> 6;       // 0..7 -> col tile
    int kg   = lane >> 4;      // 0..3
    int lr   = lane & 15;
    int c    = (wid << 4) + lr;

    // prefetch fp32 carry values early (latency hides under staging + MFMA)
    float ho[2][4];
    #pragma unroll
    for (int t = 0; t < 2; ++t)
        #pragma unroll
        for (int q = 0; q < 4; ++q)
            ho[t][q] = h[(size_t)(i0 + t*16 + (kg << 2) + q)*HDIM + c];

    // stage S,h tiles (bf16, XOR-swizzled rows: byte ^= (row&7)<<4 breaks 256B-stride conflicts)
    {
        int srow = tid >> 4;
        int cb = (tid & 15) << 4;
        int pb = srow*256 + (cb ^ ((srow & 7) << 4));
        float4 vs = *(const float4*)((const char*)S_bf + (size_t)(i0 + srow)*256 + cb);
        float4 vh = *(const float4*)((const char*)h_bf + (size_t)(i0 + srow)*256 + cb);
        *(float4*)((char*)Sl + pb) = vs;
        *(float4*)((char*)Hl + pb) = vh;
        if (tid < GRU_M) Dl[tid] = (float)deg[i0 + tid];
    }
    __syncthreads();

    f32x4 a_cr[2], a_cz[2], a_cn[2], a_hr[2], a_hz[2], a_hn[2];
    #pragma unroll
    for (int t = 0; t < 2; ++t) {
        a_cr[t] = (f32x4){0,0,0,0}; a_cz[t] = (f32x4){0,0,0,0}; a_cn[t] = (f32x4){0,0,0,0};
        a_hr[t] = (f32x4){0,0,0,0}; a_hz[t] = (f32x4){0,0,0,0}; a_hn[t] = (f32x4){0,0,0,0};
    }

    int r0 = lr, r1 = 16 + lr;
    int x0 = (r0 & 7) << 4, x1 = (r1 & 7) << 4;

    #pragma unroll
    for (int kc = 0; kc < 4; ++kc) {
        int cb = kc*64 + kg*16;
        bf16x8 aS0 = *(const bf16x8*)((const char*)Sl + r0*256 + (cb ^ x0));
        bf16x8 aS1 = *(const bf16x8*)((const char*)Sl + r1*256 + (cb ^ x1));
        bf16x8 aH0 = *(const bf16x8*)((const char*)Hl + r0*256 + (cb ^ x0));
        bf16x8 aH1 = *(const bf16x8*)((const char*)Hl + r1*256 + (cb ^ x1));
        const bf16x8* Bc = (const bf16x8*)Wc + (size_t)kc*1536 + lane;
        const bf16x8* Bh = (const bf16x8*)Wh + (size_t)kc*1536 + lane;
        bf16x8 b;
        b = Bc[(size_t)(wid     ) * 64];
        a_cr[0] = __builtin_amdgcn_mfma_f32_16x16x32_bf16(aS0, b, a_cr[0], 0, 0, 0);
        a_cr[1] = __builtin_amdgcn_mfma_f32_16x16x32_bf16(aS1, b, a_cr[1], 0, 0, 0);
        b = Bc[(size_t)(wid +  8) * 64];
        a_cz[0] = __builtin_amdgcn_mfma_f32_16x16x32_bf16(aS0, b, a_cz[0], 0, 0, 0);
        a_cz[1] = __builtin_amdgcn_mfma_f32_16x16x32_bf16(aS1, b, a_cz[1], 0, 0, 0);
        b = Bc[(size_t)(wid + 16) * 64];
        a_cn[0] = __builtin_amdgcn_mfma_f32_16x16x32_bf16(aS0, b, a_cn[0], 0, 0, 0);
        a_cn[1] = __builtin_amdgcn_mfma_f32_16x16x32_bf16(aS1, b, a_cn[1], 0, 0, 0);
        b = Bh[(size_t)(wid     ) * 64];
        a_hr[0] = __builtin_amdgcn_mfma_f32_16x16x32_bf16(aH0, b, a_hr[0], 0, 0, 0);
        a_hr[1] = __builtin_amdgcn_mfma_f32_16x16x32_bf16(aH1, b, a_hr[1], 0, 0, 0);
        b = Bh[(size_t)(wid +  8) * 64];
        a_hz[0] = __builtin_amdgcn_mfma_f32_16x16x32_bf16(aH0, b, a_hz[0], 0, 0, 0);
        a_hz[1] = __builtin_amdgcn_mfma_f32_16x16x32_bf16(aH1, b, a_hz[1], 0, 0, 0);
        b = Bh[(size_t)(wid + 16) * 64];
        a_hn[0] = __builtin_amdgcn_mfma_f32_16x16x32_bf16(aH0, b, a_hn[0], 0, 0, 0);
        a_hn[1] = __builtin_amdgcn_mfma_f32_16x16x32_bf16(aH1, b, a_hn[1], 0, 0, 0);
    }

    // per-column constants (r,z combine b_ih+b_hh; n keeps them separate)
    float bc_r = b_c[c],  bc_z = b_c[c+128],  bc_n = b_c[c+256];
    float bs_r = b_ih[c]     + b_hh[c];
    float bs_z = b_ih[c+128] + b_hh[c+128];
    float bi_n = b_ih[c+256], bh_n = b_hh[c+256];

    #pragma unroll
    for (int t = 0; t < 2; ++t) {
        #pragma unroll
        for (int q = 0; q < 4; ++q) {
            int row = t*16 + (kg << 2) + q;
            int node = i0 + row;
            float dg = Dl[row];
            float r  = fast_sigmoid(a_cr[t][q] + a_hr[t][q] + fmaf(dg, bc_r, bs_r));
            float z  = fast_sigmoid(a_cz[t][q] + a_hz[t][q] + fmaf(dg, bc_z, bs_z));
            float gin = a_cn[t][q] + fmaf(dg, bc_n, bi_n);
            float ghn = a_hn[t][q] + bh_n;
            float nn = fast_tanh(fmaf(r, ghn, gin));
            size_t p = (size_t)node*HDIM + c;
            float hv = fmaf(z, ho[t][q] - nn, nn);
            h[p] = hv;
            h_bf[p] = f2bf(hv);
        }
    }
}

extern "C" void kernel_launch(void* const* d_in, const int* in_sizes, int n_in,
                              void* d_out, int out_size, void* d_ws, size_t ws_size,
                              hipStream_t stream)
{
    const float* x     = (const float*)d_in[0];
    const int*   eidx  = (const int*)d_in[1];
    const float* W_msg = (const float*)d_in[2];
    const float* b_msg = (const float*)d_in[3];
    const float* W_ih  = (const float*)d_in[4];
    const float* W_hh  = (const float*)d_in[5];
    const float* b_ih  = (const float*)d_in[6];
    const float* b_hh  = (const float*)d_in[7];

    float* h = (float*)d_out;

    char* ws = (char*)d_ws;
    size_t off = 0;
    auto alloc = [&](size_t bytes) -> void* {
        void* p = ws + off;
        off = (off + bytes + 255) & ~(size_t)255;
        return p;
    };
    unsigned short* S_bf = (unsigned short*)alloc((size_t)N_NODESC*HDIM*sizeof(unsigned short));
    unsigned short* h_bf = (unsigned short*)alloc((size_t)N_NODESC*HDIM*sizeof(unsigned short));
    unsigned short* Wc   = (unsigned short*)alloc((size_t)HDIM*H3*sizeof(unsigned short));
    unsigned short* Wh   = (unsigned short*)alloc((size_t)HDIM*H3*sizeof(unsigned short));
    float* b_c    = (float*)alloc(H3*sizeof(float));
    int*   deg    = (int*)alloc((N_NODESC+1)*sizeof(int));
    int*   offs   = (int*)alloc((N_NODESC+1)*sizeof(int));
    int*   cur    = (int*)alloc(N_NODESC*sizeof(int));
    int*   cols   = (int*)alloc(N_EDGESC*sizeof(int));
    int*   bsums  = (int*)alloc(256*sizeof(int));

    hipMemsetAsync(deg, 0, (N_NODESC+1)*sizeof(int), stream);

    init_h<<<(N_NODESC*HDIM/4 + 255)/256, 256, 0, stream>>>(x, h, h_bf);
    prep_pack<<<(HDIM*H3 + 255)/256, 256, 0, stream>>>(W_msg, b_msg, W_ih, W_hh, Wc, Wh, b_c);

    hist_kernel<<<(N_EDGESC + 255)/256, 256, 0, stream>>>(eidx, deg);

    int n_scan = N_NODESC + 1;
    int nb = (n_scan + SCAN_CHUNK - 1) / SCAN_CHUNK;
    scan_partial<<<nb, SCAN_BLOCK, 0, stream>>>(deg, offs, bsums, n_scan);
    scan_sums<<<1, 64, 0, stream>>>(bsums, nb);
    scan_add<<<(n_scan + 255)/256, 256, 0, stream>>>(offs, bsums, n_scan);

    copy_cursor<<<(N_NODESC + 255)/256, 256, 0, stream>>>(offs, cur);
    scatter_edges<<<(N_EDGESC + 255)/256, 256, 0, stream>>>(eidx, cur, cols);

    for (int step = 0; step < NUM_STEPSC; ++step) {
        agg_bf16<<<N_NODESC/4, 256, 0, stream>>>(h_bf, offs, cols, S_bf);
        gru_mfma<<<N_NODESC/GRU_M, 512, 0, stream>>>(S_bf, h, h_bf, deg, Wc, Wh, b_c, b_ih, b_hh);
    }
}

// Round 8
// 435.496 us; speedup vs baseline: 7.0428x; 1.3308x over previous
//
#include <hip/hip_runtime.h>

#define N_NODESC 100000
#define N_EDGESC 600000
#define HDIM 128
#define H3 384
#define NUM_STEPSC 5

#define SCAN_BLOCK 256
#define SCAN_CHUNK 1024

typedef __attribute__((ext_vector_type(8))) short bf16x8;
typedef __attribute__((ext_vector_type(4))) float f32x4;

__device__ __forceinline__ unsigned short f2bf(float x) {
    union { float f; unsigned int u; } v; v.f = x;
    unsigned int r = v.u + 0x7FFF + ((v.u >> 16) & 1);
    return (unsigned short)(r >> 16);
}
__device__ __forceinline__ float bf2f(unsigned short lo16) {
    union { unsigned int u; float f; } v; v.u = (unsigned int)lo16 << 16; return v.f;
}

// hardware gates: v_exp_f32 computes 2^x, v_rcp_f32 ~1ulp. Saturation at +/-inf is exact.
__device__ __forceinline__ float fast_sigmoid(float x) {
    float e = __builtin_amdgcn_exp2f(-1.44269504f * x);
    return __builtin_amdgcn_rcpf(1.0f + e);
}
__device__ __forceinline__ float fast_tanh(float x) {
    float e = __builtin_amdgcn_exp2f(2.88539008f * x);
    return 1.0f - 2.0f * __builtin_amdgcn_rcpf(1.0f + e);
}

// ---- weight prep: W_c = W_ih @ W_msg (fused), pack W_c and W_hh^T into MFMA B-frag layout ----
// B-frag layout for mfma_f32_16x16x32_bf16: lane = (k_in_tile/8)*16 + (j&15), elem e = k_in_tile&7.
// flat index: ((kt*24 + jt)*64 + lane)*8 + e   (kt = k>>5, jt = j>>4)
__global__ void prep_pack(const float* __restrict__ W_msg, const float* __restrict__ b_msg,
                          const float* __restrict__ W_ih, const float* __restrict__ W_hh,
                          unsigned short* __restrict__ Wc, unsigned short* __restrict__ Wh,
                          float* __restrict__ b_c)
{
    int tid = blockIdx.x * blockDim.x + threadIdx.x;
    if (tid >= HDIM * H3) return;
    int j = tid % H3;   // output col 0..383
    int k = tid / H3;   // input dim 0..127
    float wc = 0.f;
    for (int m = 0; m < HDIM; ++m)
        wc = fmaf(W_ih[j*HDIM + m], W_msg[m*HDIM + k], wc);
    float wh = W_hh[j*HDIM + k];
    int kt = k >> 5, kk = k & 31, jt = j >> 4, jj = j & 15;
    int lane = ((kk >> 3) << 4) + jj;
    int e = kk & 7;
    size_t idx = ((size_t)(kt*24 + jt)*64 + lane)*8 + e;
    Wc[idx] = f2bf(wc);
    Wh[idx] = f2bf(wh);
    if (k == 0) {
        float bb = 0.f;
        for (int m = 0; m < HDIM; ++m) bb = fmaf(W_ih[j*HDIM + m], b_msg[m], bb);
        b_c[j] = bb;
    }
}

// ---- h_bf init: bf16 shadow of x (fp32 h is only materialized on the last step) ----
__global__ void init_hbf(const float* __restrict__ x, unsigned short* __restrict__ h_bf)
{
    int i = blockIdx.x * blockDim.x + threadIdx.x;
    if (i >= N_NODESC * HDIM / 4) return;
    float4 v = ((const float4*)x)[i];
    ushort4 b;
    b.x = f2bf(v.x); b.y = f2bf(v.y); b.z = f2bf(v.z); b.w = f2bf(v.w);
    ((ushort4*)h_bf)[i] = b;
}

// ---- CSR build ----
__global__ void hist_kernel(const int* __restrict__ eidx, int* __restrict__ deg)
{
    int e = blockIdx.x * blockDim.x + threadIdx.x;
    if (e < N_EDGESC) atomicAdd(&deg[eidx[e]], 1);
}

__global__ void scan_partial(const int* __restrict__ in, int* __restrict__ out,
                             int* __restrict__ bsums, int n)
{
    __shared__ int ts[SCAN_BLOCK];
    int tid = threadIdx.x;
    int base = blockIdx.x * SCAN_CHUNK + tid * 4;
    int v0 = (base+0 < n) ? in[base+0] : 0;
    int v1 = (base+1 < n) ? in[base+1] : 0;
    int v2 = (base+2 < n) ? in[base+2] : 0;
    int v3 = (base+3 < n) ? in[base+3] : 0;
    ts[tid] = v0+v1+v2+v3;
    __syncthreads();
    for (int off = 1; off < SCAN_BLOCK; off <<= 1) {
        int t = (tid >= off) ? ts[tid-off] : 0;
        __syncthreads();
        ts[tid] += t;
        __syncthreads();
    }
    int excl = (tid > 0) ? ts[tid-1] : 0;
    if (tid == SCAN_BLOCK-1) bsums[blockIdx.x] = ts[SCAN_BLOCK-1];
    if (base+0 < n) out[base+0] = excl;
    if (base+1 < n) out[base+1] = excl + v0;
    if (base+2 < n) out[base+2] = excl + v0 + v1;
    if (base+3 < n) out[base+3] = excl + v0 + v1 + v2;
}

__global__ void scan_sums(int* bsums, int nb)
{
    if (threadIdx.x == 0 && blockIdx.x == 0) {
        int run = 0;
        for (int b = 0; b < nb; ++b) { int t = bsums[b]; bsums[b] = run; run += t; }
    }
}

// also seeds the scatter cursor (fuses old copy_cursor)
__global__ void scan_add(int* __restrict__ out, const int* __restrict__ bsums, int n,
                         int* __restrict__ cur)
{
    int i = blockIdx.x * blockDim.x + threadIdx.x;
    if (i < n) {
        int v = out[i] + bsums[i / SCAN_CHUNK];
        out[i] = v;
        if (i < N_NODESC) cur[i] = v;
    }
}

__global__ void scatter_edges(const int* __restrict__ eidx, int* __restrict__ cur, int* __restrict__ cols)
{
    int e = blockIdx.x * blockDim.x + threadIdx.x;
    if (e < N_EDGESC) {
        int r = eidx[e];
        int c = eidx[N_EDGESC + e];
        int p = atomicAdd(&cur[r], 1);
        cols[p] = c;
    }
}

// ---- fused step: gather-aggregate + dual MFMA GEMM + GRU gates ----
// 512 threads = 8 waves, 32 nodes/block.
// Phase 1: stage own h_bf rows (Hl) and gather-sum neighbor rows straight into the
//          A-operand LDS tile (Sl), both XOR-swizzled (byte ^= (row&7)<<4).
// Phase 2: wave w owns col group c = w*16 + (lane&15) and its r/z/n tiles for BOTH GEMMs
//          -> gate math register-local in C-layout (col=lane&15, row=(lane>>4)*4+q).
// Carry h_old comes from Hl (bf16) -> no fp32 state; fp32 output written last step only.
#define GRU_M 32
__global__ __launch_bounds__(512) void gnn_step(
    const unsigned short* __restrict__ hb_src, unsigned short* __restrict__ hb_dst,
    float* __restrict__ h_out,
    const int* __restrict__ offs, const int* __restrict__ cols,
    const unsigned short* __restrict__ Wc, const unsigned short* __restrict__ Wh,
    const float* __restrict__ b_c, const float* __restrict__ b_ih, const float* __restrict__ b_hh)
{
    __shared__ unsigned short Sl[GRU_M * HDIM];
    __shared__ unsigned short Hl[GRU_M * HDIM];
    __shared__ float Dl[GRU_M];

    int tid = threadIdx.x;
    int i0 = blockIdx.x * GRU_M;

    int srow = tid >> 4;             // 0..31: node-local row
    int cb   = (tid & 15) << 4;      // byte col within 256B row
    int pb   = srow*256 + (cb ^ ((srow & 7) << 4));

    // own rows -> Hl (feeds Wh GEMM + carry)
    *(float4*)((char*)Hl + pb) =
        *(const float4*)((const char*)hb_src + (size_t)(i0 + srow)*256 + cb);

    // gather-aggregate 8 columns per lane
    int beg = offs[i0 + srow], end = offs[i0 + srow + 1];
    float acc[8] = {0.f,0.f,0.f,0.f,0.f,0.f,0.f,0.f};
    int e = beg;
    for (; e + 1 < end; e += 2) {
        int s0 = cols[e], s1 = cols[e+1];
        bf16x8 v0 = *(const bf16x8*)((const char*)hb_src + (size_t)s0*256 + cb);
        bf16x8 v1 = *(const bf16x8*)((const char*)hb_src + (size_t)s1*256 + cb);
        #pragma unroll
        for (int j = 0; j < 8; ++j) {
            acc[j] += bf2f((unsigned short)v0[j]);
            acc[j] += bf2f((unsigned short)v1[j]);
        }
    }
    if (e < end) {
        bf16x8 v0 = *(const bf16x8*)((const char*)hb_src + (size_t)cols[e]*256 + cb);
        #pragma unroll
        for (int j = 0; j < 8; ++j) acc[j] += bf2f((unsigned short)v0[j]);
    }
    union { ushort2 u2[4]; float4 f4; } pk;
    #pragma unroll
    for (int j = 0; j < 4; ++j) {
        pk.u2[j].x = f2bf(acc[2*j]);
        pk.u2[j].y = f2bf(acc[2*j+1]);
    }
    *(float4*)((char*)Sl + pb) = pk.f4;
    if ((tid & 15) == 0) Dl[srow] = (float)(end - beg);
    __syncthreads();

    int lane = tid & 63;
    int wid  = tid >> 6;       // 0..7 -> col tile
    int kg   = lane >> 4;      // 0..3
    int lr   = lane & 15;
    int c    = (wid << 4) + lr;

    f32x4 a_cr[2], a_cz[2], a_cn[2], a_hr[2], a_hz[2], a_hn[2];
    #pragma unroll
    for (int t = 0; t < 2; ++t) {
        a_cr[t] = (f32x4){0,0,0,0}; a_cz[t] = (f32x4){0,0,0,0}; a_cn[t] = (f32x4){0,0,0,0};
        a_hr[t] = (f32x4){0,0,0,0}; a_hz[t] = (f32x4){0,0,0,0}; a_hn[t] = (f32x4){0,0,0,0};
    }

    int r0 = lr, r1 = 16 + lr;
    int x0 = (r0 & 7) << 4, x1 = (r1 & 7) << 4;

    #pragma unroll
    for (int kc = 0; kc < 4; ++kc) {
        int cbk = kc*64 + kg*16;
        bf16x8 aS0 = *(const bf16x8*)((const char*)Sl + r0*256 + (cbk ^ x0));
        bf16x8 aS1 = *(const bf16x8*)((const char*)Sl + r1*256 + (cbk ^ x1));
        bf16x8 aH0 = *(const bf16x8*)((const char*)Hl + r0*256 + (cbk ^ x0));
        bf16x8 aH1 = *(const bf16x8*)((const char*)Hl + r1*256 + (cbk ^ x1));
        const bf16x8* Bc = (const bf16x8*)Wc + (size_t)kc*1536 + lane;
        const bf16x8* Bh = (const bf16x8*)Wh + (size_t)kc*1536 + lane;
        bf16x8 b;
        b = Bc[(size_t)(wid     ) * 64];
        a_cr[0] = __builtin_amdgcn_mfma_f32_16x16x32_bf16(aS0, b, a_cr[0], 0, 0, 0);
        a_cr[1] = __builtin_amdgcn_mfma_f32_16x16x32_bf16(aS1, b, a_cr[1], 0, 0, 0);
        b = Bc[(size_t)(wid +  8) * 64];
        a_cz[0] = __builtin_amdgcn_mfma_f32_16x16x32_bf16(aS0, b, a_cz[0], 0, 0, 0);
        a_cz[1] = __builtin_amdgcn_mfma_f32_16x16x32_bf16(aS1, b, a_cz[1], 0, 0, 0);
        b = Bc[(size_t)(wid + 16) * 64];
        a_cn[0] = __builtin_amdgcn_mfma_f32_16x16x32_bf16(aS0, b, a_cn[0], 0, 0, 0);
        a_cn[1] = __builtin_amdgcn_mfma_f32_16x16x32_bf16(aS1, b, a_cn[1], 0, 0, 0);
        b = Bh[(size_t)(wid     ) * 64];
        a_hr[0] = __builtin_amdgcn_mfma_f32_16x16x32_bf16(aH0, b, a_hr[0], 0, 0, 0);
        a_hr[1] = __builtin_amdgcn_mfma_f32_16x16x32_bf16(aH1, b, a_hr[1], 0, 0, 0);
        b = Bh[(size_t)(wid +  8) * 64];
        a_hz[0] = __builtin_amdgcn_mfma_f32_16x16x32_bf16(aH0, b, a_hz[0], 0, 0, 0);
        a_hz[1] = __builtin_amdgcn_mfma_f32_16x16x32_bf16(aH1, b, a_hz[1], 0, 0, 0);
        b = Bh[(size_t)(wid + 16) * 64];
        a_hn[0] = __builtin_amdgcn_mfma_f32_16x16x32_bf16(aH0, b, a_hn[0], 0, 0, 0);
        a_hn[1] = __builtin_amdgcn_mfma_f32_16x16x32_bf16(aH1, b, a_hn[1], 0, 0, 0);
    }

    // per-column constants (r,z combine b_ih+b_hh; n keeps them separate)
    float bc_r = b_c[c],  bc_z = b_c[c+128],  bc_n = b_c[c+256];
    float bs_r = b_ih[c]     + b_hh[c];
    float bs_z = b_ih[c+128] + b_hh[c+128];
    float bi_n = b_ih[c+256], bh_n = b_hh[c+256];

    #pragma unroll
    for (int t = 0; t < 2; ++t) {
        #pragma unroll
        for (int q = 0; q < 4; ++q) {
            int row = t*16 + (kg << 2) + q;
            int node = i0 + row;
            float dg = Dl[row];
            float r  = fast_sigmoid(a_cr[t][q] + a_hr[t][q] + fmaf(dg, bc_r, bs_r));
            float z  = fast_sigmoid(a_cz[t][q] + a_hz[t][q] + fmaf(dg, bc_z, bs_z));
            float gin = a_cn[t][q] + fmaf(dg, bc_n, bi_n);
            float ghn = a_hn[t][q] + bh_n;
            float nn = fast_tanh(fmaf(r, ghn, gin));
            // carry from the staged bf16 tile (swizzled LDS read)
            float hold = bf2f(*(const unsigned short*)((const char*)Hl + row*256 + ((c*2) ^ ((row & 7) << 4))));
            float hv = fmaf(z, hold - nn, nn);
            size_t p = (size_t)node*HDIM + c;
            hb_dst[p] = f2bf(hv);
            if (h_out) h_out[p] = hv;
        }
    }
}

extern "C" void kernel_launch(void* const* d_in, const int* in_sizes, int n_in,
                              void* d_out, int out_size, void* d_ws, size_t ws_size,
                              hipStream_t stream)
{
    const float* x     = (const float*)d_in[0];
    const int*   eidx  = (const int*)d_in[1];
    const float* W_msg = (const float*)d_in[2];
    const float* b_msg = (const float*)d_in[3];
    const float* W_ih  = (const float*)d_in[4];
    const float* W_hh  = (const float*)d_in[5];
    const float* b_ih  = (const float*)d_in[6];
    const float* b_hh  = (const float*)d_in[7];

    float* h = (float*)d_out;

    char* ws = (char*)d_ws;
    size_t off = 0;
    auto alloc = [&](size_t bytes) -> void* {
        void* p = ws + off;
        off = (off + bytes + 255) & ~(size_t)255;
        return p;
    };
    unsigned short* hb0 = (unsigned short*)alloc((size_t)N_NODESC*HDIM*sizeof(unsigned short));
    unsigned short* hb1 = (unsigned short*)alloc((size_t)N_NODESC*HDIM*sizeof(unsigned short));
    unsigned short* Wc  = (unsigned short*)alloc((size_t)HDIM*H3*sizeof(unsigned short));
    unsigned short* Wh  = (unsigned short*)alloc((size_t)HDIM*H3*sizeof(unsigned short));
    float* b_c    = (float*)alloc(H3*sizeof(float));
    int*   deg    = (int*)alloc((N_NODESC+1)*sizeof(int));
    int*   offs   = (int*)alloc((N_NODESC+1)*sizeof(int));
    int*   cur    = (int*)alloc(N_NODESC*sizeof(int));
    int*   cols   = (int*)alloc(N_EDGESC*sizeof(int));
    int*   bsums  = (int*)alloc(256*sizeof(int));

    hipMemsetAsync(deg, 0, (N_NODESC+1)*sizeof(int), stream);

    init_hbf<<<(N_NODESC*HDIM/4 + 255)/256, 256, 0, stream>>>(x, hb0);
    prep_pack<<<(HDIM*H3 + 255)/256, 256, 0, stream>>>(W_msg, b_msg, W_ih, W_hh, Wc, Wh, b_c);

    hist_kernel<<<(N_EDGESC + 255)/256, 256, 0, stream>>>(eidx, deg);

    int n_scan = N_NODESC + 1;
    int nb = (n_scan + SCAN_CHUNK - 1) / SCAN_CHUNK;
    scan_partial<<<nb, SCAN_BLOCK, 0, stream>>>(deg, offs, bsums, n_scan);
    scan_sums<<<1, 64, 0, stream>>>(bsums, nb);
    scan_add<<<(n_scan + 255)/256, 256, 0, stream>>>(offs, bsums, n_scan, cur);

    scatter_edges<<<(N_EDGESC + 255)/256, 256, 0, stream>>>(eidx, cur, cols);

    for (int step = 0; step < NUM_STEPSC; ++step) {
        const unsigned short* src = (step & 1) ? hb1 : hb0;
        unsigned short*       dst = (step & 1) ? hb0 : hb1;
        float* out = (step == NUM_STEPSC - 1) ? h : nullptr;
        gnn_step<<<N_NODESC/GRU_M, 512, 0, stream>>>(src, dst, out, offs, cols,
                                                     Wc, Wh, b_c, b_ih, b_hh);
    }
}